// Round 8
// baseline (1794.831 us; speedup 1.0000x reference)
//
#include <hip/hip_runtime.h>
#include <math.h>

#define HID 256
#define TWOH 512
#define ROWS 8192   // B*S
#define NLAYER 4
#define TMAX 50
#define DT 0.05f
#define EPSC 1e-3f

typedef float f32x4 __attribute__((ext_vector_type(4)));
typedef unsigned char u8;

// fp8 helpers (OCP e4m3 on gfx950)
__device__ inline u8 f32_to_fp8(float v) {
    return (u8)(__builtin_amdgcn_cvt_pk_fp8_f32(v, v, 0, 0) & 0xff);
}
__device__ inline float fp8_to_f32(u8 b) {
    return __builtin_amdgcn_cvt_f32_fp8((int)b, 0);
}

// ---------------------------------------------------------------------------
// Fragment-major fp8 weight packing for the 16-wave split.
// Wave wv owns d-range [wv*16, wv*16+16): nt=0 -> tau cols, nt=1 -> forcing.
// Fragment (L,wv,ci,nt) is 512 B contiguous: lane*8 + j; d = wv*16 + l15,
// k = ci*32 + quad*8 + j.
// e bits: j:0-2, lane:3-8, nt:9, ci:10-13, wv:14-17, L:18-19.
// tau row d: Wt[d][k]; forcing row d: k<256 ? Wi[d][k] : Ws[d][k-256].
// ---------------------------------------------------------------------------
__global__ void pack_w_kernel(const float* __restrict__ Ws,
                              const float* __restrict__ Wi,
                              const float* __restrict__ Wt,
                              u8* __restrict__ Wf) {
    int e = blockIdx.x * 256 + threadIdx.x;     // [0, 2^20)
    int j    = e & 7;
    int lane = (e >> 3) & 63;
    int nt   = (e >> 9) & 1;
    int ci   = (e >> 10) & 15;
    int wv   = (e >> 14) & 15;
    int L    = (e >> 18);
    int l15  = lane & 15;
    int quad = lane >> 4;
    int d = wv * 16 + l15;
    int k = ci * 32 + quad * 8 + j;
    float v;
    if (nt == 0) {
        v = Wt[(size_t)L * HID * TWOH + (size_t)d * TWOH + k];
    } else {
        v = (k < HID) ? Wi[(size_t)L * HID * HID + (size_t)d * HID + k]
                      : Ws[(size_t)L * HID * HID + (size_t)d * HID + (k - HID)];
    }
    Wf[e] = f32_to_fp8(v);
}

__global__ void pack_b_kernel(const float* __restrict__ bs,
                              const float* __restrict__ bi,
                              const float* __restrict__ bt,
                              float* __restrict__ bp) {
    int idx = blockIdx.x * 256 + threadIdx.x;   // [0, 4*512): L*512 + 2d(+1)
    int L = idx / TWOH;
    int n = idx % TWOH;
    int d = n >> 1;
    bp[idx] = ((n & 1) == 0) ? bt[L * HID + d]
                             : (bs[L * HID + d] + bi[L * HID + d]);
}

// ---------------------------------------------------------------------------
// Persistent kernel, 1024 threads (16 waves -> 4 waves/SIMD).
// Block b owns rows [32b, 32b+32) for all 50 t x 4 layers. States are
// LDS-resident fp8, PING-PONG buffered (read sH[pt], write sH[pt^1]) ->
// ONE barrier per layer-step. Weights stream L2 -> registers as 512-B
// fragments; the ci>=12 tail prefetches the NEXT layer-step's first groups
// (modulo-scheduled, zero extra registers) so the memory pipe never drains.
// ---------------------------------------------------------------------------
__global__ __launch_bounds__(1024, 1) void persistent_kernel(
    const float* __restrict__ x,
    const u8* __restrict__ Wf,
    const float* __restrict__ bp,
    float* __restrict__ deltas,
    float* __restrict__ out)
{
    __shared__ u8 sX[32 * 256];              //  8 KB
    __shared__ u8 sH[2][NLAYER][32 * 256];   // 64 KB (ping-pong states)
    __shared__ float2 sBias[NLAYER][256];    //  8 KB
    __shared__ float sRed[16];
    __shared__ u8 sPad[16384];               // 16 KB pad -> ~96 KB: 1 block/CU

    const int tid  = threadIdx.x;
    const int lane = tid & 63;
    const int wv   = tid >> 6;               // 0..15
    const int l15  = lane & 15;
    const int quad = lane >> 4;              // 0..3
    const int w16  = wv * 16;                // wave's d-base
    const size_t rowbase = (size_t)blockIdx.x * 32;

    // ---- stage x -> sX (fp8, swizzled); zero both sH buffers; bias table ----
    {
        int r = tid >> 5, seg = tid & 31;    // 32 rows x 32 segs
        const float* gx = x + (rowbase + r) * HID + seg * 8;
        float4 v0 = *(const float4*)gx;
        float4 v1 = *(const float4*)(gx + 4);
        int lo = __builtin_amdgcn_cvt_pk_fp8_f32(v0.x, v0.y, 0, 0);
        lo     = __builtin_amdgcn_cvt_pk_fp8_f32(v0.z, v0.w, lo, 1);
        int hi = __builtin_amdgcn_cvt_pk_fp8_f32(v1.x, v1.y, 0, 0);
        hi     = __builtin_amdgcn_cvt_pk_fp8_f32(v1.z, v1.w, hi, 1);
        long pk = ((long)(unsigned int)lo) | ((long)hi << 32);
        *(long*)&sX[r * 256 + (seg ^ r) * 8] = pk;
    }
    {
        long* hflat = (long*)&sH[0][0][0];   // 8192 longs total
        #pragma unroll
        for (int it = 0; it < 8; ++it) hflat[tid + it * 1024] = 0;
    }
    sBias[tid >> 8][tid & 255] = *(const float2*)(bp + (tid >> 8) * TWOH + 2 * (tid & 255));
    {
        volatile u8* vp = sPad;              // keep pad allocated
        vp[tid] = 0;
    }
    __syncthreads();

    // ---- preload weight fragment groups 0..3 of (t=0, L=0) ----
    long bb[4][2];
    {
        const u8* wb0 = Wf + (size_t)wv * 16384 + (size_t)lane * 8;
        #pragma unroll
        for (int pi = 0; pi < 4; ++pi)
            #pragma unroll
            for (int nt = 0; nt < 2; ++nt)
                bb[pi][nt] = *(const long*)(wb0 + (size_t)(pi * 2 + nt) * 512);
    }

    for (int t = 0; t < TMAX; ++t) {
        const int pt = t & 1;
        float dmax = 0.0f;
        for (int L = 0; L < NLAYER; ++L) {
            const u8* Alo  = (L == 0) ? sX : sH[pt ^ 1][L - 1]; // k<256: cur_in (this t)
            const u8* Ahi  = sH[pt][L];                         // k>=256: h_prev (last t)
            u8*       Hdst = sH[pt ^ 1][L];                     // h_new
            const u8* wbc = Wf + (size_t)(L * 16 + wv) * 16384 + (size_t)lane * 8;
            const u8* wbn = Wf + (size_t)((((L + 1) & 3) * 16) + wv) * 16384 + (size_t)lane * 8;

            f32x4 acc[2][2];
            #pragma unroll
            for (int mt = 0; mt < 2; ++mt)
                #pragma unroll
                for (int nt = 0; nt < 2; ++nt)
                    acc[mt][nt] = (f32x4){0.f, 0.f, 0.f, 0.f};

            #pragma unroll
            for (int ci = 0; ci < 16; ++ci) {            // k = 32*ci
                const int p = ci & 3;
                const u8* Asrc = (ci < 8) ? Alo : Ahi;   // static under unroll
                const int seg = (ci & 7) * 4 + quad;     // 8-B seg in [0,32)
                long a[2];
                #pragma unroll
                for (int mt = 0; mt < 2; ++mt) {
                    int row = mt * 16 + l15;
                    a[mt] = *(const long*)&Asrc[row * 256 + ((seg ^ row) * 8)];
                }
                #pragma unroll
                for (int mt = 0; mt < 2; ++mt)
                    #pragma unroll
                    for (int nt = 0; nt < 2; ++nt)
                        acc[mt][nt] = __builtin_amdgcn_mfma_f32_16x16x32_fp8_fp8(
                            a[mt], bb[p][nt], acc[mt][nt], 0, 0, 0);
                // modulo-scheduled prefetch: this layer's groups ci+4, then
                // the NEXT layer-step's groups 0..3 (stay in flight across
                // the barrier).
                if (ci < 12) {
                    #pragma unroll
                    for (int nt = 0; nt < 2; ++nt)
                        bb[p][nt] = *(const long*)(wbc + (size_t)((ci + 4) * 2 + nt) * 512);
                } else {
                    #pragma unroll
                    for (int nt = 0; nt < 2; ++nt)
                        bb[p][nt] = *(const long*)(wbn + (size_t)((ci - 12) * 2 + nt) * 512);
                }
            }

            // Epilogue (no barrier needed before it: writes go to the pong
            // buffer). C/D: col = l15, row = quad*4+reg. tau in acc[mt][0],
            // forcing in acc[mt][1] -- same lane, same d.
            {
                const int d = w16 + l15;
                const float2 bb2 = sBias[L][d];
                const int seg = d >> 3, dlow = d & 7;
                #pragma unroll
                for (int mt = 0; mt < 2; ++mt) {
                    #pragma unroll
                    for (int r = 0; r < 4; ++r) {
                        float tpre = acc[mt][0][r] + bb2.x;
                        float fpre = acc[mt][1][r] + bb2.y;
                        tpre = fminf(30.f, fmaxf(-30.f, tpre));
                        fpre = fminf(15.f, fmaxf(-15.f, fpre));
                        // h/(sigma(t)+1e-6) == h*(1+u)/(1+eps+eps*u), u=e^-t
                        float u   = __expf(-tpre);
                        float den = 1.0f + 1e-6f + 1e-6f * u;
                        float rcp = __builtin_amdgcn_rcpf(den);
                        float e2  = __expf(2.0f * fpre);
                        float r2  = __builtin_amdgcn_rcpf(e2 + 1.0f);
                        float fo  = (e2 - 1.0f) * r2;
                        const int row = mt * 16 + quad * 4 + r;
                        const int idx = row * 256 + (seg ^ row) * 8 + dlow;
                        float h  = fp8_to_f32(Ahi[idx]);
                        float g  = h * (1.0f + u) * rcp;
                        float nv = h + DT * (fo - g);
                        nv = fminf(10.0f, fmaxf(-10.0f, nv));
                        Hdst[idx] = f32_to_fp8(nv);
                        dmax = fmaxf(dmax, fabsf(nv - h));
                    }
                }
            }
            if (L == NLAYER - 1) {
                #pragma unroll
                for (int off = 32; off > 0; off >>= 1)
                    dmax = fmaxf(dmax, __shfl_xor(dmax, off));
                if (lane == 0) sRed[wv] = dmax;
            }
            __syncthreads();   // ONE barrier per layer-step: h_new visible
        } // L

        if (tid == 0) {
            float m = sRed[0];
            #pragma unroll
            for (int w = 1; w < 16; ++w) m = fmaxf(m, sRed[w]);
            atomicMax((unsigned int*)(deltas + t), __float_as_uint(m));
        }
    } // t

    // ---- final output: layer-3 states (in sH[0] after t=49), fp8 -> fp32 ----
    {
        int r = tid >> 5, seg = tid & 31;
        long v = *(const long*)&sH[0][NLAYER - 1][r * 256 + (seg ^ r) * 8];
        int lo = (int)(v & 0xffffffffl);
        int hi = (int)(v >> 32);
        float* go = out + (rowbase + r) * HID + seg * 8;
        float4 o0, o1;
        o0.x = __builtin_amdgcn_cvt_f32_fp8(lo, 0);
        o0.y = __builtin_amdgcn_cvt_f32_fp8(lo, 1);
        o0.z = __builtin_amdgcn_cvt_f32_fp8(lo, 2);
        o0.w = __builtin_amdgcn_cvt_f32_fp8(lo, 3);
        o1.x = __builtin_amdgcn_cvt_f32_fp8(hi, 0);
        o1.y = __builtin_amdgcn_cvt_f32_fp8(hi, 1);
        o1.z = __builtin_amdgcn_cvt_f32_fp8(hi, 2);
        o1.w = __builtin_amdgcn_cvt_f32_fp8(hi, 3);
        *(float4*)go = o0;
        *(float4*)(go + 4) = o1;
    }
}

__global__ void result_kernel(const float* __restrict__ deltas,
                              float* __restrict__ out) {
    if (threadIdx.x == 0) {
        int res = TMAX;
        for (int t = 0; t < TMAX; ++t) {
            if (deltas[t] < EPSC) { res = t; break; }
        }
        out[(size_t)ROWS * HID] = (float)res;
    }
}

// ---------------------------------------------------------------------------
extern "C" void kernel_launch(void* const* d_in, const int* in_sizes, int n_in,
                              void* d_out, int out_size, void* d_ws, size_t ws_size,
                              hipStream_t stream) {
    const float* x  = (const float*)d_in[0];
    const float* Ws = (const float*)d_in[1];
    const float* bs = (const float*)d_in[2];
    const float* Wi = (const float*)d_in[3];
    const float* bi = (const float*)d_in[4];
    const float* Wt = (const float*)d_in[5];
    const float* bt = (const float*)d_in[6];
    float* out = (float*)d_out;

    char* p = (char*)d_ws;
    u8*    Wf     = (u8*)p;    p += (size_t)NLAYER * TWOH * TWOH;            // 1 MB
    float* bp     = (float*)p; p += (size_t)NLAYER * TWOH * sizeof(float);   // 8 KB
    float* deltas = (float*)p; p += 64 * sizeof(float);

    hipMemsetAsync(deltas, 0, 64 * sizeof(float), stream);
    pack_w_kernel<<<(NLAYER * TWOH * TWOH) / 256, 256, 0, stream>>>(Ws, Wi, Wt, Wf);
    pack_b_kernel<<<(NLAYER * TWOH) / 256, 256, 0, stream>>>(bs, bi, bt, bp);

    persistent_kernel<<<256, 1024, 0, stream>>>(x, Wf, bp, deltas, out);
    result_kernel<<<1, 64, 0, stream>>>(deltas, out);
}